// Round 1
// baseline (123.092 us; speedup 1.0000x reference)
//
#include <hip/hip_runtime.h>
#include <math.h>

#define N_SAMPLES 16384
#define FEAT 2048
#define NCLS 1000
#define CPAD 1024

// ---------------- workspace layout (floats/ints) ----------------
// sums      : float[NCLS*FEAT]     per-class feature sums
// snorm     : float[CPAD]          ||sums_c||
// overall   : float[FEAT]          sum over all samples (Σ_i x_i)
// scalars   : float[4]             {||overall||, st_sum, sw_sum, pad}
// counts    : int[CPAD]
// offsets   : int[CPAD]
// cursor    : int[CPAD]
// perm      : int[N_SAMPLES]

__global__ void zero_kernel(float* overall, float* scalars, int* counts) {
  int t = threadIdx.x;
  for (int i = t; i < FEAT; i += 256) overall[i] = 0.f;
  for (int i = t; i < CPAD; i += 256) counts[i] = 0;
  if (t < 4) scalars[t] = 0.f;
}

__global__ void hist_kernel(const int* __restrict__ labels, int* __restrict__ counts) {
  for (int i = blockIdx.x * blockDim.x + threadIdx.x; i < N_SAMPLES;
       i += gridDim.x * blockDim.x)
    atomicAdd(&counts[labels[i]], 1);
}

// exclusive scan over CPAD=1024 counts, single block of 1024 threads
__global__ void scan_kernel(const int* __restrict__ counts, int* __restrict__ offsets,
                            int* __restrict__ cursor) {
  __shared__ int buf0[CPAD], buf1[CPAD];
  int t = threadIdx.x;
  buf0[t] = counts[t];
  __syncthreads();
  int* src = buf0;
  int* dst = buf1;
  for (int off = 1; off < CPAD; off <<= 1) {
    dst[t] = src[t] + (t >= off ? src[t - off] : 0);
    __syncthreads();
    int* tmp = src; src = dst; dst = tmp;
  }
  int excl = (t == 0) ? 0 : src[t - 1];
  offsets[t] = excl;
  cursor[t] = excl;
}

__global__ void scatter_kernel(const int* __restrict__ labels, int* __restrict__ cursor,
                               int* __restrict__ perm) {
  for (int i = blockIdx.x * blockDim.x + threadIdx.x; i < N_SAMPLES;
       i += gridDim.x * blockDim.x) {
    int pos = atomicAdd(&cursor[labels[i]], 1);
    perm[pos] = i;
  }
}

// one block per class: sum its rows (coalesced float4), write sums + ||sums||
__global__ __launch_bounds__(256) void class_sum_kernel(
    const float* __restrict__ feat, const int* __restrict__ offsets,
    const int* __restrict__ counts, const int* __restrict__ perm,
    float* __restrict__ sums, float* __restrict__ snorm) {
  int c = blockIdx.x, t = threadIdx.x;
  int beg = offsets[c], n = counts[c];
  float a0 = 0, a1 = 0, a2 = 0, a3 = 0, b0 = 0, b1 = 0, b2 = 0, b3 = 0;
  for (int r = 0; r < n; ++r) {
    const float4* row = (const float4*)(feat + (size_t)perm[beg + r] * FEAT);
    float4 v0 = row[t];
    float4 v1 = row[t + 256];
    a0 += v0.x; a1 += v0.y; a2 += v0.z; a3 += v0.w;
    b0 += v1.x; b1 += v1.y; b2 += v1.z; b3 += v1.w;
  }
  float4* sr = (float4*)(sums + (size_t)c * FEAT);
  sr[t] = make_float4(a0, a1, a2, a3);
  sr[t + 256] = make_float4(b0, b1, b2, b3);
  float sq = a0 * a0 + a1 * a1 + a2 * a2 + a3 * a3 +
             b0 * b0 + b1 * b1 + b2 * b2 + b3 * b3;
  for (int off = 32; off; off >>= 1) sq += __shfl_xor(sq, off);
  __shared__ float red[4];
  int w = t >> 6, lane = t & 63;
  if (lane == 0) red[w] = sq;
  __syncthreads();
  if (t == 0) snorm[c] = sqrtf(red[0] + red[1] + red[2] + red[3]);
}

// overall[d] = sum over classes of sums[c][d]; 64 blocks = 8 d-chunks x 8 c-chunks
__global__ __launch_bounds__(256) void overall_kernel(const float* __restrict__ sums,
                                                      float* __restrict__ overall) {
  int dchunk = blockIdx.x & 7;
  int cchunk = blockIdx.x >> 3;
  int d = dchunk * 256 + threadIdx.x;
  float acc = 0.f;
  int cbeg = cchunk * 125, cend = cbeg + 125;
  for (int c = cbeg; c < cend; ++c) acc += sums[(size_t)c * FEAT + d];
  atomicAdd(&overall[d], acc);
}

__global__ __launch_bounds__(256) void ovnorm_kernel(const float* __restrict__ overall,
                                                     float* __restrict__ scalars) {
  int t = threadIdx.x;
  float sq = 0.f;
  for (int k = 0; k < 8; ++k) {
    float v = overall[t + 256 * k];
    sq += v * v;
  }
  for (int off = 32; off; off >>= 1) sq += __shfl_xor(sq, off);
  __shared__ float red[4];
  int w = t >> 6, lane = t & 63;
  if (lane == 0) red[w] = sq;
  __syncthreads();
  if (t == 0) scalars[0] = sqrtf(red[0] + red[1] + red[2] + red[3]);
}

// one wave per row: dot(x, overall_sum), dot(x, sums[label]), ||x||^2
__global__ __launch_bounds__(256) void main_kernel(
    const float* __restrict__ feat, const int* __restrict__ labels,
    const float* __restrict__ sums, const float* __restrict__ snorm,
    const float* __restrict__ overall, const int* __restrict__ counts,
    float* __restrict__ scalars) {
  const int t = threadIdx.x, w = t >> 6, lane = t & 63;
  const int nwaves = gridDim.x * 4;
  float st_acc = 0.f, sw_acc = 0.f;
  const float ovn = scalars[0];
  const float4* ov = (const float4*)overall;
  const float invN2 = 1.f / ((float)N_SAMPLES * (float)N_SAMPLES);
  for (int row = blockIdx.x * 4 + w; row < N_SAMPLES; row += nwaves) {
    int l = labels[row];
    const float4* xr = (const float4*)(feat + (size_t)row * FEAT);
    const float4* srw = (const float4*)(sums + (size_t)l * FEAT);
    float dxo = 0.f, dxs = 0.f, nx2 = 0.f;
#pragma unroll
    for (int k = 0; k < 8; ++k) {
      float4 x = xr[lane + 64 * k];
      float4 s = srw[lane + 64 * k];
      float4 o = ov[lane + 64 * k];
      dxo += x.x * o.x + x.y * o.y + x.z * o.z + x.w * o.w;
      dxs += x.x * s.x + x.y * s.y + x.z * s.z + x.w * s.w;
      nx2 += x.x * x.x + x.y * x.y + x.z * x.z + x.w * x.w;
    }
    for (int off = 32; off; off >>= 1) {
      dxo += __shfl_xor(dxo, off);
      dxs += __shfl_xor(dxs, off);
      nx2 += __shfl_xor(nx2, off);
    }
    float nx = sqrtf(nx2);
    float cnt = (float)counts[l];
    // cdist(x, overall_mean) = 1 - dot(x, ovsum)/N * (||ovsum||/N) / ||x||
    float t1 = 1.f - dxo * ovn * invN2 / nx;
    // d = 1 - dot(x, sums_l)/cnt * (||sums_l||/cnt) / ||x||
    float t2 = 1.f - dxs * snorm[l] / (cnt * cnt * nx);
    st_acc += t1 * t1;
    sw_acc += t2 * t2;
  }
  __shared__ float red[8];
  if (lane == 0) { red[w] = st_acc; red[4 + w] = sw_acc; }
  __syncthreads();
  if (t == 0) {
    atomicAdd(&scalars[1], red[0] + red[1] + red[2] + red[3]);
    atomicAdd(&scalars[2], red[4] + red[5] + red[6] + red[7]);
  }
}

__global__ void finalize_kernel(const float* __restrict__ scalars,
                                float* __restrict__ out) {
  if (threadIdx.x == 0) {
    float st = scalars[1] / (float)N_SAMPLES;
    float sw = scalars[2] / ((float)N_SAMPLES * (float)NCLS);
    out[0] = st;
    out[1] = sw;
    out[2] = st - sw;
  }
}

extern "C" void kernel_launch(void* const* d_in, const int* in_sizes, int n_in,
                              void* d_out, int out_size, void* d_ws, size_t ws_size,
                              hipStream_t stream) {
  const float* feat = (const float*)d_in[0];
  const int* labels = (const int*)d_in[1];
  float* out = (float*)d_out;

  float* sums = (float*)d_ws;                   // NCLS*FEAT
  float* snorm = sums + (size_t)NCLS * FEAT;    // CPAD
  float* overall = snorm + CPAD;                // FEAT
  float* scalars = overall + FEAT;              // 4
  int* counts = (int*)(scalars + 4);            // CPAD
  int* offsets = counts + CPAD;                 // CPAD
  int* cursor = offsets + CPAD;                 // CPAD
  int* perm = cursor + CPAD;                    // N_SAMPLES

  zero_kernel<<<1, 256, 0, stream>>>(overall, scalars, counts);
  hist_kernel<<<64, 256, 0, stream>>>(labels, counts);
  scan_kernel<<<1, 1024, 0, stream>>>(counts, offsets, cursor);
  scatter_kernel<<<64, 256, 0, stream>>>(labels, cursor, perm);
  class_sum_kernel<<<NCLS, 256, 0, stream>>>(feat, offsets, counts, perm, sums, snorm);
  overall_kernel<<<64, 256, 0, stream>>>(sums, overall);
  ovnorm_kernel<<<1, 256, 0, stream>>>(overall, scalars);
  main_kernel<<<1024, 256, 0, stream>>>(feat, labels, sums, snorm, overall, counts,
                                        scalars);
  finalize_kernel<<<1, 1, 0, stream>>>(scalars, out);
}